// Round 5
// baseline (701.100 us; speedup 1.0000x reference)
//
#include <hip/hip_runtime.h>

#define L_N   16384
#define B_N   4
#define M_N   256
#define HID_N 512
#define PI_F  3.14159265358979323846f

typedef short short8 __attribute__((ext_vector_type(8)));
typedef ushort us4 __attribute__((ext_vector_type(4)));
typedef float f32x4 __attribute__((ext_vector_type(4)));

__device__ __forceinline__ ushort f2bf(float f) {
  uint u = __float_as_uint(f);
  uint r = u + 0x7FFF + ((u >> 16) & 1);
  return (ushort)(r >> 16);
}
__device__ __forceinline__ float bf2f(ushort s) {
  return __uint_as_float(((uint)s) << 16);
}
__device__ __forceinline__ void gld_lds16(const void* g, void* s) {
  __builtin_amdgcn_global_load_lds((const __attribute__((address_space(1))) void*)g,
                                   (__attribute__((address_space(3))) void*)s, 16, 0, 0);
}

// ---------- merged weight transpose: fp32 [R][C] -> bf16 [C][R] ----------
__global__ __launch_bounds__(256) void k_wt_all(
    const float* __restrict__ w_query, const float* __restrict__ w_to_q,
    const float* __restrict__ w_to_kv, const float* __restrict__ w_to_out,
    const float* __restrict__ w_band, const float* __restrict__ w_mod,
    const float* __restrict__ w_hv,
    ushort* __restrict__ wq_t, ushort* __restrict__ wtq_t,
    ushort* __restrict__ wkv_t, ushort* __restrict__ wto_t,
    ushort* __restrict__ wb_t, ushort* __restrict__ wm_t, ushort* __restrict__ whv_t) {
  __shared__ float t[32][33];
  int tb = blockIdx.x;
  const float* in; ushort* out; int R, C;
  if (tb < 64)        { in = w_query;  out = wq_t;  R = 128; C = 512; }
  else if (tb < 128)  { tb -= 64;  in = w_to_q;   out = wtq_t; R = 512; C = 128; }
  else if (tb < 256)  { tb -= 128; in = w_to_kv;  out = wkv_t; R = 512; C = 256; }
  else if (tb < 320)  { tb -= 256; in = w_to_out; out = wto_t; R = 128; C = 512; }
  else if (tb < 512)  { tb -= 320; int kk = tb >> 6; tb &= 63;
                        in = w_band + (size_t)kk * 65536; out = wb_t + (size_t)kk * 65536; R = 128; C = 512; }
  else if (tb < 1280) { tb -= 512; int kk = tb >> 8; tb &= 255;
                        in = w_mod + (size_t)kk * 262144; out = wm_t + (size_t)kk * 262144; R = 512; C = 512; }
  else                { tb -= 1280; int kk = tb >> 8; tb &= 255;
                        in = w_hv + (size_t)kk * 262144; out = whv_t + (size_t)kk * 262144; R = 512; C = 512; }
  int nbx = C >> 5;
  int bx = (tb % nbx) * 32, by = (tb / nbx) * 32;
  int tx = threadIdx.x & 31, ty = threadIdx.x >> 5;
#pragma unroll
  for (int j = 0; j < 32; j += 8) t[ty + j][tx] = in[(size_t)(by + ty + j) * C + bx + tx];
  __syncthreads();
#pragma unroll
  for (int j = 0; j < 32; j += 8)
    out[(size_t)(bx + ty + j) * R + by + tx] = f2bf(t[tx][ty + j]);
}

// ---------- fp32 -> bf16 elementwise ----------
__global__ __launch_bounds__(256) void k_cvt(const float* __restrict__ in,
                                             ushort* __restrict__ out, int n4) {
  int i = blockIdx.x * 256 + threadIdx.x;
  if (i >= n4) return;
  float4 v = *(const float4*)&in[(size_t)i * 4];
  ushort* o = &out[(size_t)i * 4];
  o[0] = f2bf(v.x); o[1] = f2bf(v.y); o[2] = f2bf(v.z); o[3] = f2bf(v.w);
}

// ---------- gamma: [4 specs][L][128] bf16 ----------
__global__ __launch_bounds__(256) void k_gamma(const float* __restrict__ x,
                                               ushort* __restrict__ gout) {
  __shared__ float om[16];
  const float lgs[4] = {2.1072099696478683f, 2.1072099696478683f,
                        1.5051499783199058f, 0.9030899869919435f};
  int spec = blockIdx.y;
  float lg = lgs[spec];
  int tid = threadIdx.x;
  if (tid < 16) om[tid] = powf(10.0f, 1.0f + (float)tid * ((lg - 1.0f) * (1.0f / 15.0f)));
  __syncthreads();
  int l0 = blockIdx.x * 16;
  int idx0 = tid * 8;
  int row = idx0 >> 7, f0 = idx0 & 127;
  int c = f0 >> 5;
  float g = x[(size_t)(l0 + row) * 4 + c];
  float base = PI_F * g;
  int w0 = f0 & 31;
  bool is_cos = (w0 >= 16);
  short8 o;
#pragma unroll
  for (int j = 0; j < 8; ++j) {
    int jf = (w0 + j) & 15;
    float arg = base * om[jf];
    float v = is_cos ? __cosf(arg) : __sinf(arg);
    o[j] = (short)f2bf(v);
  }
  *(short8*)&gout[(size_t)spec * L_N * 128 + (size_t)(l0 + row) * 128 + f0] = o;
}

// ---------- t positions ----------
__global__ __launch_bounds__(256) void k_tpos(const float* __restrict__ x,
                                              const int* dD, const int* dH,
                                              const int* dW, const int* dT,
                                              float* __restrict__ tbuf) {
  int l = blockIdx.x * 256 + threadIdx.x;
  float g0 = x[(size_t)l * 4 + 0], g1 = x[(size_t)l * 4 + 1];
  float g2 = x[(size_t)l * 4 + 2], g3 = x[(size_t)l * 4 + 3];
  int Dd = dD[0], Hh = dH[0], Ww = dW[0], Tt = dT[0];
  int zi = (int)(g0 * (float)Dd), yi = (int)(g1 * (float)Hh);
  int xi = (int)(g2 * (float)Ww), ti = (int)(g3 * (float)Tt);
  int idx = ((ti * Dd + zi) * Hh + yi) * Ww + xi;
  tbuf[l] = (float)idx / (float)(Dd * Hh * Ww * Tt);
}

// ---------- generic bf16 MFMA GEMM (for small pre-pass GEMMs) ----------
__global__ __launch_bounds__(256, 4) void k_gemm2(
    const ushort* __restrict__ A, long long sA,
    const ushort* __restrict__ Wt,
    const float* __restrict__ bias,
    ushort* C, long long sC,
    int N, int K, int do_relu) {
  __shared__ __align__(16) ushort S[128 * 64 * 2];
  ushort* As = S;
  ushort* Ws = S + 128 * 64;
  int tid = threadIdx.x;
  int lane = tid & 63, wid = tid >> 6;
  int n0 = blockIdx.x * 128, r0 = blockIdx.y * 128;
  int z = blockIdx.z;
  A += (size_t)z * sA;
  C += (size_t)z * sC;
  int wr = wid >> 1, wc = wid & 1;
  int ksm = K >> 6;

  f32x4 acc[4][4];
#pragma unroll
  for (int i = 0; i < 4; ++i)
#pragma unroll
    for (int j = 0; j < 4; ++j) acc[i][j] = (f32x4)0.0f;

  for (int t = 0; t < ksm; ++t) {
#pragma unroll
    for (int j = 0; j < 4; ++j) {
      int sig = j * 256 + wid * 64 + lane;
      int r = sig >> 3, ph = sig & 7, sl = ph ^ (r & 7);
      gld_lds16(&A[(size_t)(r0 + r) * K + t * 64 + sl * 8], &As[(size_t)(j * 256 + wid * 64) * 8]);
      gld_lds16(&Wt[(size_t)(n0 + r) * K + t * 64 + sl * 8], &Ws[(size_t)(j * 256 + wid * 64) * 8]);
    }
    __syncthreads();
#pragma unroll
    for (int ks = 0; ks < 2; ++ks) {
      short8 af[4], bg[4];
#pragma unroll
      for (int fm = 0; fm < 4; ++fm) {
        int row = wr * 64 + fm * 16 + (lane & 15);
        af[fm] = *(const short8*)&As[row * 64 + (((ks * 4 + (lane >> 4)) ^ (row & 7)) * 8)];
      }
#pragma unroll
      for (int fn = 0; fn < 4; ++fn) {
        int nl = wc * 64 + fn * 16 + (lane & 15);
        bg[fn] = *(const short8*)&Ws[nl * 64 + (((ks * 4 + (lane >> 4)) ^ (nl & 7)) * 8)];
      }
#pragma unroll
      for (int fm = 0; fm < 4; ++fm)
#pragma unroll
        for (int fn = 0; fn < 4; ++fn)
          acc[fm][fn] = __builtin_amdgcn_mfma_f32_16x16x32_bf16(af[fm], bg[fn], acc[fm][fn], 0, 0, 0);
    }
    __syncthreads();
  }
  float* Ls = (float*)S;
  int row = tid >> 3;
  int c0 = (tid & 7) * 16;
#pragma unroll
  for (int fm = 0; fm < 4; ++fm) {
    if (fm) __syncthreads();
#pragma unroll
    for (int fn = 0; fn < 4; ++fn)
#pragma unroll
      for (int reg = 0; reg < 4; ++reg) {
        int lr = wr * 16 + (lane >> 4) * 4 + reg;
        int lc = wc * 64 + fn * 16 + (lane & 15);
        Ls[lr * 132 + lc] = acc[fm][fn][reg];
      }
    __syncthreads();
    int gr = r0 + (row >> 4) * 64 + fm * 16 + (row & 15);
#pragma unroll
    for (int hh = 0; hh < 2; ++hh) {
      int cc = c0 + hh * 8;
      float v[8];
#pragma unroll
      for (int j = 0; j < 8; ++j) v[j] = Ls[row * 132 + cc + j];
      if (bias) {
#pragma unroll
        for (int j = 0; j < 8; ++j) v[j] += bias[n0 + cc + j];
      }
      if (do_relu) {
#pragma unroll
        for (int j = 0; j < 8; ++j) v[j] = fmaxf(v[j], 0.0f);
      }
      short8 ov;
#pragma unroll
      for (int j = 0; j < 8; ++j) ov[j] = (short)f2bf(v[j]);
      *(short8*)&C[(size_t)gr * N + n0 + cc] = ov;
    }
  }
}

// ---------- kv rearrange ----------
__global__ __launch_bounds__(256) void k_rearr(const ushort* __restrict__ kvtmp,
                                               ushort* __restrict__ kbuf,
                                               ushort* __restrict__ vtb) {
  int i = blockIdx.x * 256 + threadIdx.x;
  int col = i & 255, row = i >> 8;
  int b = row >> 8, m = row & 255;
  ushort v = kvtmp[i];
  if (col < 128)
    kbuf[((size_t)b * 256 + m) * 128 + col] = v;
  else
    vtb[(size_t)b * 128 * 256 + (size_t)(col - 128) * 256 + m] = v;
}

// ---------- MFMA attention per (b, head) ----------
__global__ __launch_bounds__(256) void k_attn_m(const ushort* __restrict__ qbuf,
                                                const float* __restrict__ tbuf,
                                                const ushort* __restrict__ kbuf,
                                                const ushort* __restrict__ vtb,
                                                ushort* __restrict__ attn) {
  __shared__ __align__(16) ushort Kt[256 * 64];
  __shared__ __align__(16) ushort Vt[64 * 256];
  __shared__ __align__(16) ushort Qs[64 * 64];
  __shared__ __align__(16) ushort Pw[4][16 * 40];
  __shared__ float ts[64];
  int tid = threadIdx.x;
  int lane = tid & 63, wid = tid >> 6;
  int l0 = blockIdx.x * 64;
  int h = blockIdx.y;
  int z = blockIdx.z;
  const ushort* kbuf_b = kbuf + (size_t)z * M_N * 128;
  const ushort* vtb_b = vtb + (size_t)z * 128 * M_N;
  ushort* attn_b = attn + (size_t)z * L_N * 128;
#pragma unroll
  for (int j = 0; j < 8; ++j) {
    int sig = j * 256 + wid * 64 + lane;
    int m = sig >> 3, ph = sig & 7, sl = ph ^ (m & 7);
    gld_lds16(&kbuf_b[(size_t)m * 128 + h * 64 + sl * 8], &Kt[(size_t)(j * 256 + wid * 64) * 8]);
  }
#pragma unroll
  for (int j = 0; j < 8; ++j) {
    int sig = j * 256 + wid * 64 + lane;
    int d = sig >> 5, ph = sig & 31, sl = ph ^ ((d & 7) << 2);
    gld_lds16(&vtb_b[(size_t)(h * 64 + d) * 256 + sl * 8], &Vt[(size_t)(j * 256 + wid * 64) * 8]);
  }
#pragma unroll
  for (int j = 0; j < 2; ++j) {
    int sig = j * 256 + wid * 64 + lane;
    int q = sig >> 3, ph = sig & 7, sl = ph ^ (q & 7);
    gld_lds16(&qbuf[(size_t)(l0 + q) * 128 + h * 64 + sl * 8], &Qs[(size_t)(j * 256 + wid * 64) * 8]);
  }
  if (tid < 64) ts[tid] = tbuf[l0 + tid];
  __syncthreads();

  f32x4 s_acc[16];
#pragma unroll
  for (int fn = 0; fn < 16; ++fn) s_acc[fn] = (f32x4)0.0f;
#pragma unroll
  for (int ks = 0; ks < 2; ++ks) {
    int qrow = wid * 16 + (lane & 15);
    short8 aq = *(const short8*)&Qs[qrow * 64 + (((ks * 4 + (lane >> 4)) ^ (qrow & 7)) * 8)];
#pragma unroll
    for (int fn = 0; fn < 16; ++fn) {
      int m = fn * 16 + (lane & 15);
      short8 bk = *(const short8*)&Kt[m * 64 + (((ks * 4 + (lane >> 4)) ^ (m & 7)) * 8)];
      s_acc[fn] = __builtin_amdgcn_mfma_f32_16x16x32_bf16(aq, bk, s_acc[fn], 0, 0, 0);
    }
  }
  float mx[4] = {-1e30f, -1e30f, -1e30f, -1e30f};
#pragma unroll
  for (int fn = 0; fn < 16; ++fn) {
#pragma unroll
    for (int reg = 0; reg < 4; ++reg) {
      int ql = wid * 16 + (lane >> 4) * 4 + reg;
      int m = fn * 16 + (lane & 15);
      float mp = ((float)m + 0.5f) * (1.0f / 256.0f);
      float d = ts[ql] - mp;
      float v = s_acc[fn][reg] * 0.125f - 10.0f * d * d;
      s_acc[fn][reg] = v;
      mx[reg] = fmaxf(mx[reg], v);
    }
  }
#pragma unroll
  for (int reg = 0; reg < 4; ++reg) {
    mx[reg] = fmaxf(mx[reg], __shfl_xor(mx[reg], 1));
    mx[reg] = fmaxf(mx[reg], __shfl_xor(mx[reg], 2));
    mx[reg] = fmaxf(mx[reg], __shfl_xor(mx[reg], 4));
    mx[reg] = fmaxf(mx[reg], __shfl_xor(mx[reg], 8));
  }
  float sm[4] = {0.0f, 0.0f, 0.0f, 0.0f};
#pragma unroll
  for (int fn = 0; fn < 16; ++fn) {
#pragma unroll
    for (int reg = 0; reg < 4; ++reg) {
      float e = __expf(s_acc[fn][reg] - mx[reg]);
      s_acc[fn][reg] = e;
      sm[reg] += e;
    }
  }
#pragma unroll
  for (int reg = 0; reg < 4; ++reg) {
    sm[reg] += __shfl_xor(sm[reg], 1);
    sm[reg] += __shfl_xor(sm[reg], 2);
    sm[reg] += __shfl_xor(sm[reg], 4);
    sm[reg] += __shfl_xor(sm[reg], 8);
  }
  float inv[4];
#pragma unroll
  for (int reg = 0; reg < 4; ++reg) inv[reg] = 1.0f / sm[reg];

  f32x4 o_acc[4];
#pragma unroll
  for (int fn = 0; fn < 4; ++fn) o_acc[fn] = (f32x4)0.0f;
  for (int kk = 0; kk < 8; ++kk) {
#pragma unroll
    for (int fp = 0; fp < 2; ++fp) {
      int fn = kk * 2 + fp;
#pragma unroll
      for (int reg = 0; reg < 4; ++reg) {
        int ql16 = (lane >> 4) * 4 + reg;
        int mc = fp * 16 + (lane & 15);
        Pw[wid][ql16 * 40 + mc] = f2bf(s_acc[fn][reg] * inv[reg]);
      }
    }
    asm volatile("s_waitcnt lgkmcnt(0)" ::: "memory");
    __builtin_amdgcn_sched_barrier(0);
    short8 pa = *(const short8*)&Pw[wid][(lane & 15) * 40 + (lane >> 4) * 8];
#pragma unroll
    for (int fn = 0; fn < 4; ++fn) {
      int dr = fn * 16 + (lane & 15);
      short8 vb = *(const short8*)&Vt[dr * 256 + (((kk * 4 + (lane >> 4)) ^ ((dr & 7) << 2)) * 8)];
      o_acc[fn] = __builtin_amdgcn_mfma_f32_16x16x32_bf16(pa, vb, o_acc[fn], 0, 0, 0);
    }
    asm volatile("s_waitcnt lgkmcnt(0)" ::: "memory");
    __builtin_amdgcn_sched_barrier(0);
  }
#pragma unroll
  for (int fn = 0; fn < 4; ++fn)
#pragma unroll
    for (int reg = 0; reg < 4; ++reg) {
      int ql = l0 + wid * 16 + (lane >> 4) * 4 + reg;
      attn_b[(size_t)ql * 128 + h * 64 + fn * 16 + (lane & 15)] = f2bf(o_acc[fn][reg]);
    }
}

// ---------- fused chain: per 64-row tile, whole kk=0..2 chain in one block ----------
// Operand-swapped MFMA: A := weight rows (n), B := activation rows (r)
// D: n = nf*16 + (lane>>4)*4 + reg, r = rf*16 + (lane&15)
__global__ __launch_bounds__(512, 2) void k_chain(
    const ushort* __restrict__ modv, long long sModv,
    const ushort* __restrict__ gamma1,   // spec-1 base ([3 specs][L][128] follow)
    const ushort* __restrict__ wm_t, const ushort* __restrict__ wb_t,
    const ushort* __restrict__ whv_t,
    const float* __restrict__ b_mod, const float* __restrict__ b_band,
    const float* __restrict__ b_hv,
    const float* __restrict__ w_out, const float* __restrict__ b_out,
    float* __restrict__ out, int zoff) {
  __shared__ __align__(16) ushort mL[64 * 512];    // 64 KB, 8 chunks [64r][64c swz]
  __shared__ __align__(16) ushort hvL[64 * 512];   // 64 KB
  __shared__ __align__(16) ushort stg[2][64 * 64]; // 16 KB dbuf
  int tid = threadIdx.x;
  int lane = tid & 63, wv = tid >> 6;   // wave wv owns n in [wv*64, wv*64+64)
  int r0 = blockIdx.x * 64;
  int zl = blockIdx.y;
  int z = zl + zoff;
  const ushort* modz = modv + (size_t)zl * sModv;
  float oa0 = 0.0f, oa1 = 0.0f, oa2 = 0.0f;
  int srow = tid >> 3, ssl = (tid & 7) ^ (srow & 7);

  for (int kk = 0; kk < 3; ++kk) {
    const ushort* wm = wm_t + (size_t)kk * 262144;
    const ushort* wb = wb_t + (size_t)kk * 65536;
    const ushort* gz = gamma1 + (size_t)kk * ((size_t)L_N * 128);
    f32x4 acc[4][4], acc2[4][4];
#pragma unroll
    for (int i = 0; i < 4; ++i)
#pragma unroll
      for (int j = 0; j < 4; ++j) { acc[i][j] = (f32x4)0.0f; acc2[i][j] = (f32x4)0.0f; }

    // ---- m-GEMM: acc = modv@wm^T (t=0..7), acc2 = gamma@wb^T (t=8..9) ----
    gld_lds16(&modz[(size_t)(r0 + srow) * 512 + ssl * 8], &stg[0][tid * 8]);
    asm volatile("s_waitcnt vmcnt(0)" ::: "memory");
    __syncthreads();
    int cur = 0;
    for (int t = 0; t < 10; ++t) {
      if (t < 9) {
        if (t < 7)
          gld_lds16(&modz[(size_t)(r0 + srow) * 512 + (t + 1) * 64 + ssl * 8], &stg[cur ^ 1][tid * 8]);
        else
          gld_lds16(&gz[(size_t)(r0 + srow) * 128 + (t - 7) * 64 + ssl * 8], &stg[cur ^ 1][tid * 8]);
      }
      const ushort* wsrc = (t < 8) ? wm : wb;
      int ldw = (t < 8) ? 512 : 128;
      int koff = (t < 8) ? t * 64 : (t - 8) * 64;
#pragma unroll
      for (int ks = 0; ks < 2; ++ks) {
        short8 af[4], bg[4];
#pragma unroll
        for (int nf = 0; nf < 4; ++nf) {
          int n = wv * 64 + nf * 16 + (lane & 15);
          af[nf] = *(const short8*)&wsrc[(size_t)n * ldw + koff + ks * 32 + (lane >> 4) * 8];
        }
#pragma unroll
        for (int rf = 0; rf < 4; ++rf) {
          int rr = rf * 16 + (lane & 15);
          bg[rf] = *(const short8*)&stg[cur][rr * 64 + (((ks * 4 + (lane >> 4)) ^ (rr & 7)) * 8)];
        }
        if (t < 8) {
#pragma unroll
          for (int nf = 0; nf < 4; ++nf)
#pragma unroll
            for (int rf = 0; rf < 4; ++rf)
              acc[nf][rf] = __builtin_amdgcn_mfma_f32_16x16x32_bf16(af[nf], bg[rf], acc[nf][rf], 0, 0, 0);
        } else {
#pragma unroll
          for (int nf = 0; nf < 4; ++nf)
#pragma unroll
            for (int rf = 0; rf < 4; ++rf)
              acc2[nf][rf] = __builtin_amdgcn_mfma_f32_16x16x32_bf16(af[nf], bg[rf], acc2[nf][rf], 0, 0, 0);
        }
      }
      asm volatile("s_waitcnt vmcnt(0)" ::: "memory");
      __syncthreads();
      cur ^= 1;
    }

    // ---- m-epilogue: e = relu(relu(acc2+bb) + acc + bm) [+ hv]; -> mL (kk>0) / hvL (kk==0)
    {
      ushort* dst = (kk == 0) ? hvL : mL;
#pragma unroll
      for (int nf = 0; nf < 4; ++nf) {
#pragma unroll
        for (int rf = 0; rf < 4; ++rf) {
          int r = rf * 16 + (lane & 15);
          int nb = wv * 64 + nf * 16 + (lane >> 4) * 4;
          float4 bb4 = *(const float4*)&b_band[kk * 512 + nb];
          float4 bm4 = *(const float4*)&b_mod[kk * 512 + nb];
          float bbv[4] = {bb4.x, bb4.y, bb4.z, bb4.w};
          float bmv[4] = {bm4.x, bm4.y, bm4.z, bm4.w};
          int c = nb & 63;
          int addr = (nb >> 6) * 4096 + r * 64 + (((c >> 3) ^ (r & 7)) * 8) + (c & 7);
          float v[4];
#pragma unroll
          for (int j = 0; j < 4; ++j) {
            float h = fmaxf(acc2[nf][rf][j] + bbv[j], 0.0f);
            v[j] = fmaxf(h + acc[nf][rf][j] + bmv[j], 0.0f);
          }
          if (kk > 0) {
            us4 hv4 = *(const us4*)&hvL[addr];
#pragma unroll
            for (int j = 0; j < 4; ++j) v[j] += bf2f(hv4[j]);
          }
          us4 pv;
#pragma unroll
          for (int j = 0; j < 4; ++j) pv[j] = f2bf(v[j]);
          *(us4*)&dst[addr] = pv;
        }
      }
    }
    __syncthreads();

    // ---- hv-GEMM (kk>0): hv = relu(s@whv^T + bhv), s in mL (barrier-free K-loop) ----
    if (kk > 0) {
      const ushort* wh = whv_t + (size_t)(kk - 1) * 262144;
#pragma unroll
      for (int i = 0; i < 4; ++i)
#pragma unroll
        for (int j = 0; j < 4; ++j) acc[i][j] = (f32x4)0.0f;
      for (int t = 0; t < 8; ++t) {
#pragma unroll
        for (int ks = 0; ks < 2; ++ks) {
          short8 af[4], bg[4];
#pragma unroll
          for (int nf = 0; nf < 4; ++nf) {
            int n = wv * 64 + nf * 16 + (lane & 15);
            af[nf] = *(const short8*)&wh[(size_t)n * 512 + t * 64 + ks * 32 + (lane >> 4) * 8];
          }
#pragma unroll
          for (int rf = 0; rf < 4; ++rf) {
            int rr = rf * 16 + (lane & 15);
            bg[rf] = *(const short8*)&mL[t * 4096 + rr * 64 + (((ks * 4 + (lane >> 4)) ^ (rr & 7)) * 8)];
          }
#pragma unroll
          for (int nf = 0; nf < 4; ++nf)
#pragma unroll
            for (int rf = 0; rf < 4; ++rf)
              acc[nf][rf] = __builtin_amdgcn_mfma_f32_16x16x32_bf16(af[nf], bg[rf], acc[nf][rf], 0, 0, 0);
        }
      }
#pragma unroll
      for (int nf = 0; nf < 4; ++nf) {
#pragma unroll
        for (int rf = 0; rf < 4; ++rf) {
          int r = rf * 16 + (lane & 15);
          int nb = wv * 64 + nf * 16 + (lane >> 4) * 4;
          float4 bh4 = *(const float4*)&b_hv[(kk - 1) * 512 + nb];
          float bhv[4] = {bh4.x, bh4.y, bh4.z, bh4.w};
          int c = nb & 63;
          int addr = (nb >> 6) * 4096 + r * 64 + (((c >> 3) ^ (r & 7)) * 8) + (c & 7);
          us4 pv;
#pragma unroll
          for (int j = 0; j < 4; ++j) pv[j] = f2bf(fmaxf(acc[nf][rf][j] + bhv[j], 0.0f));
          *(us4*)&hvL[addr] = pv;
        }
      }
    }
    __syncthreads();

    // ---- out-pass: oa += hv @ w_out[kk] ----
    {
      int orow = tid >> 3, och = tid & 7;
      float s0 = 0.0f, s1 = 0.0f, s2 = 0.0f;
#pragma unroll
      for (int p = 0; p < 8; ++p) {
        short8 hval = *(const short8*)&hvL[och * 4096 + orow * 64 + p * 8];
        int cbase = och * 64 + ((p ^ (orow & 7)) * 8);
        const float* wo = &w_out[kk * 1536 + cbase * 3];
#pragma unroll
        for (int j = 0; j < 8; ++j) {
          float hvv = bf2f((ushort)hval[j]);
          s0 = fmaf(hvv, wo[j * 3 + 0], s0);
          s1 = fmaf(hvv, wo[j * 3 + 1], s1);
          s2 = fmaf(hvv, wo[j * 3 + 2], s2);
        }
      }
      s0 += __shfl_down(s0, 4); s1 += __shfl_down(s1, 4); s2 += __shfl_down(s2, 4);
      s0 += __shfl_down(s0, 2); s1 += __shfl_down(s1, 2); s2 += __shfl_down(s2, 2);
      s0 += __shfl_down(s0, 1); s1 += __shfl_down(s1, 1); s2 += __shfl_down(s2, 1);
      if ((tid & 7) == 0) { oa0 += s0; oa1 += s1; oa2 += s2; }
    }
    // next kk's m-loop prologue barrier protects stg/mL/hvL reuse
  }

  if ((tid & 7) == 0) {
    int l = r0 + (tid >> 3);
    float* po = &out[((size_t)z * L_N + l) * 3];
    po[0] = oa0 + b_out[0] + b_out[3] + b_out[6];
    po[1] = oa1 + b_out[1] + b_out[4] + b_out[7];
    po[2] = oa2 + b_out[2] + b_out[5] + b_out[8];
  }
}

extern "C" void kernel_launch(void* const* d_in, const int* in_sizes, int n_in,
                              void* d_out, int out_size, void* d_ws, size_t ws_size,
                              hipStream_t stream) {
  const float* x        = (const float*)d_in[0];
  const float* tokens   = (const float*)d_in[1];
  const float* w_query  = (const float*)d_in[2];
  const float* b_query  = (const float*)d_in[3];
  const float* w_to_q   = (const float*)d_in[4];
  const float* w_to_kv  = (const float*)d_in[5];
  const float* w_to_out = (const float*)d_in[6];
  const float* b_to_out = (const float*)d_in[7];
  const float* w_band   = (const float*)d_in[8];
  const float* b_band   = (const float*)d_in[9];
  const float* w_mod    = (const float*)d_in[10];
  const float* b_mod    = (const float*)d_in[11];
  const float* w_hv     = (const float*)d_in[12];
  const float* b_hv     = (const float*)d_in[13];
  const float* w_out    = (const float*)d_in[14];
  const float* b_out    = (const float*)d_in[15];
  const int* Dd = (const int*)d_in[16];
  const int* Hh = (const int*)d_in[17];
  const int* Ww = (const int*)d_in[18];
  const int* Tt = (const int*)d_in[19];
  float* out = (float*)d_out;

  ushort* W = (ushort*)d_ws;
  size_t o = 0;
  auto alloc = [&](size_t n) { ushort* p = W + o; o += n; return p; };
  const size_t big = (size_t)L_N * HID_N;   // 8388608
  const size_t LQ = (size_t)L_N * 128;

  ushort* gamma  = alloc(4 * LQ);
  ushort* qb     = alloc(LQ);
  ushort* attnout= alloc(4 * LQ);
  ushort* tokb   = alloc((size_t)B_N * M_N * HID_N);
  ushort* kbuf   = alloc((size_t)B_N * M_N * 128);
  ushort* vtb    = alloc((size_t)B_N * 128 * M_N);
  ushort* wq_t   = alloc(512 * 128);
  ushort* wtq_t  = alloc(128 * 512);
  ushort* wkv_t  = alloc(256 * 512);
  ushort* wto_t  = alloc(512 * 128);
  ushort* wb_t   = alloc(3 * 512 * 128);
  ushort* wm_t   = alloc(3 * 512 * 512);
  ushort* whv_t  = alloc(2 * 512 * 512);
  float* tbuf    = (float*)alloc(L_N * 2);
  size_t base_u = o;

  bool batched = ws_size >= (base_u + 4 * big) * sizeof(ushort);
  ushort* modv = alloc(batched ? 4 * big : big);
  ushort* xq = modv;        // alias: xq dead before modv written
  ushort* kvtmp = attnout;  // alias: consumed before attnout written

  const long long SL = (long long)big;
  const long long SQ = (long long)LQ;

  // ---- prep ----
  k_wt_all<<<dim3(1792), 256, 0, stream>>>(w_query, w_to_q, w_to_kv, w_to_out, w_band, w_mod, w_hv,
                                           wq_t, wtq_t, wkv_t, wto_t, wb_t, wm_t, whv_t);
  k_cvt<<<dim3(512), 256, 0, stream>>>(tokens, tokb, B_N * M_N * HID_N / 4);
  k_gamma<<<dim3(L_N / 16, 4), 256, 0, stream>>>(x, gamma);
  k_tpos<<<dim3(L_N / 256), 256, 0, stream>>>(x, Dd, Hh, Ww, Tt, tbuf);

  // ---- pre-pass ----
  k_gemm2<<<dim3(4, 128, 1), 256, 0, stream>>>(gamma, 0, wq_t, b_query, xq, 0, 512, 128, 1);
  k_gemm2<<<dim3(1, 128, 1), 256, 0, stream>>>(xq, 0, wtq_t, nullptr, qb, 0, 128, 512, 0);
  k_gemm2<<<dim3(2, 8, 1), 256, 0, stream>>>(tokb, 0, wkv_t, nullptr, kvtmp, 0, 256, 512, 0);
  k_rearr<<<dim3(1024), 256, 0, stream>>>(kvtmp, kbuf, vtb);
  k_attn_m<<<dim3(L_N / 64, 2, 4), 256, 0, stream>>>(qb, tbuf, kbuf, vtb, attnout);

  if (batched) {
    k_gemm2<<<dim3(4, 128, 4), 256, 0, stream>>>(attnout, SQ, wto_t, b_to_out, modv, SL, 512, 128, 0);
    k_chain<<<dim3(L_N / 64, 4), 512, 0, stream>>>(modv, SL, gamma + LQ, wm_t, wb_t, whv_t,
                                                   b_mod, b_band, b_hv, w_out, b_out, out, 0);
  } else {
    for (int z = 0; z < B_N; ++z) {
      k_gemm2<<<dim3(4, 128, 1), 256, 0, stream>>>(attnout + (size_t)z * LQ, 0, wto_t, b_to_out,
                                                   modv, 0, 512, 128, 0);
      k_chain<<<dim3(L_N / 64, 1), 512, 0, stream>>>(modv, 0, gamma + LQ, wm_t, wb_t, whv_t,
                                                     b_mod, b_band, b_hv, w_out, b_out, out, z);
    }
  }
}

// Round 6
// 437.930 us; speedup vs baseline: 1.6009x; 1.6009x over previous
//
#include <hip/hip_runtime.h>

#define L_N   16384
#define B_N   4
#define M_N   256
#define HID_N 512
#define PI_F  3.14159265358979323846f

typedef short short8 __attribute__((ext_vector_type(8)));
typedef float f32x4 __attribute__((ext_vector_type(4)));

__device__ __forceinline__ ushort f2bf(float f) {
  uint u = __float_as_uint(f);
  uint r = u + 0x7FFF + ((u >> 16) & 1);
  return (ushort)(r >> 16);
}
__device__ __forceinline__ float bf2f(ushort s) {
  return __uint_as_float(((uint)s) << 16);
}
__device__ __forceinline__ void gld_lds16(const void* g, void* s) {
  __builtin_amdgcn_global_load_lds((const __attribute__((address_space(1))) void*)g,
                                   (__attribute__((address_space(3))) void*)s, 16, 0, 0);
}

// ---------- merged weight transpose: fp32 [R][C] -> bf16 [C][R] ----------
__global__ __launch_bounds__(256) void k_wt_all(
    const float* __restrict__ w_query, const float* __restrict__ w_to_q,
    const float* __restrict__ w_to_kv, const float* __restrict__ w_to_out,
    const float* __restrict__ w_band, const float* __restrict__ w_mod,
    const float* __restrict__ w_hv,
    ushort* __restrict__ wq_t, ushort* __restrict__ wtq_t,
    ushort* __restrict__ wkv_t, ushort* __restrict__ wto_t,
    ushort* __restrict__ wb_t, ushort* __restrict__ wm_t, ushort* __restrict__ whv_t) {
  __shared__ float t[32][33];
  int tb = blockIdx.x;
  const float* in; ushort* out; int R, C;
  if (tb < 64)        { in = w_query;  out = wq_t;  R = 128; C = 512; }
  else if (tb < 128)  { tb -= 64;  in = w_to_q;   out = wtq_t; R = 512; C = 128; }
  else if (tb < 256)  { tb -= 128; in = w_to_kv;  out = wkv_t; R = 512; C = 256; }
  else if (tb < 320)  { tb -= 256; in = w_to_out; out = wto_t; R = 128; C = 512; }
  else if (tb < 512)  { tb -= 320; int kk = tb >> 6; tb &= 63;
                        in = w_band + (size_t)kk * 65536; out = wb_t + (size_t)kk * 65536; R = 128; C = 512; }
  else if (tb < 1280) { tb -= 512; int kk = tb >> 8; tb &= 255;
                        in = w_mod + (size_t)kk * 262144; out = wm_t + (size_t)kk * 262144; R = 512; C = 512; }
  else                { tb -= 1280; int kk = tb >> 8; tb &= 255;
                        in = w_hv + (size_t)kk * 262144; out = whv_t + (size_t)kk * 262144; R = 512; C = 512; }
  int nbx = C >> 5;
  int bx = (tb % nbx) * 32, by = (tb / nbx) * 32;
  int tx = threadIdx.x & 31, ty = threadIdx.x >> 5;
#pragma unroll
  for (int j = 0; j < 32; j += 8) t[ty + j][tx] = in[(size_t)(by + ty + j) * C + bx + tx];
  __syncthreads();
#pragma unroll
  for (int j = 0; j < 32; j += 8)
    out[(size_t)(bx + ty + j) * R + by + tx] = f2bf(t[tx][ty + j]);
}

// ---------- fp32 -> bf16 elementwise ----------
__global__ __launch_bounds__(256) void k_cvt(const float* __restrict__ in,
                                             ushort* __restrict__ out, int n4) {
  int i = blockIdx.x * 256 + threadIdx.x;
  if (i >= n4) return;
  float4 v = *(const float4*)&in[(size_t)i * 4];
  ushort* o = &out[(size_t)i * 4];
  o[0] = f2bf(v.x); o[1] = f2bf(v.y); o[2] = f2bf(v.z); o[3] = f2bf(v.w);
}

// ---------- gamma: [4 specs][L][128] bf16 ----------
__global__ __launch_bounds__(256) void k_gamma(const float* __restrict__ x,
                                               ushort* __restrict__ gout) {
  __shared__ float om[16];
  const float lgs[4] = {2.1072099696478683f, 2.1072099696478683f,
                        1.5051499783199058f, 0.9030899869919435f};
  int spec = blockIdx.y;
  float lg = lgs[spec];
  int tid = threadIdx.x;
  if (tid < 16) om[tid] = powf(10.0f, 1.0f + (float)tid * ((lg - 1.0f) * (1.0f / 15.0f)));
  __syncthreads();
  int l0 = blockIdx.x * 16;
  int idx0 = tid * 8;
  int row = idx0 >> 7, f0 = idx0 & 127;
  int c = f0 >> 5;
  float g = x[(size_t)(l0 + row) * 4 + c];
  float base = PI_F * g;
  int w0 = f0 & 31;
  bool is_cos = (w0 >= 16);
  short8 o;
#pragma unroll
  for (int j = 0; j < 8; ++j) {
    int jf = (w0 + j) & 15;
    float arg = base * om[jf];
    float v = is_cos ? __cosf(arg) : __sinf(arg);
    o[j] = (short)f2bf(v);
  }
  *(short8*)&gout[(size_t)spec * L_N * 128 + (size_t)(l0 + row) * 128 + f0] = o;
}

// ---------- t positions ----------
__global__ __launch_bounds__(256) void k_tpos(const float* __restrict__ x,
                                              const int* dD, const int* dH,
                                              const int* dW, const int* dT,
                                              float* __restrict__ tbuf) {
  int l = blockIdx.x * 256 + threadIdx.x;
  float g0 = x[(size_t)l * 4 + 0], g1 = x[(size_t)l * 4 + 1];
  float g2 = x[(size_t)l * 4 + 2], g3 = x[(size_t)l * 4 + 3];
  int Dd = dD[0], Hh = dH[0], Ww = dW[0], Tt = dT[0];
  int zi = (int)(g0 * (float)Dd), yi = (int)(g1 * (float)Hh);
  int xi = (int)(g2 * (float)Ww), ti = (int)(g3 * (float)Tt);
  int idx = ((ti * Dd + zi) * Hh + yi) * Ww + xi;
  tbuf[l] = (float)idx / (float)(Dd * Hh * Ww * Tt);
}

// ---------- generic bf16 MFMA GEMM, 128x128 tile, BK=64, single-buffer LDS ----------
// C = [relu](A@Wt^T + bias + add1) [+ add2]; optional fused w_out partials.
// Flattened 1D grid with bijective XCD swizzle; decomp (nbx, nby, nz).
__global__ __launch_bounds__(256, 4) void k_gemm2(
    const ushort* __restrict__ A, long long sA,
    const ushort* __restrict__ Wt,
    const float* __restrict__ bias,
    const ushort* __restrict__ add1,
    const ushort* add2, long long sAdd2,
    ushort* C, long long sC,
    const float* __restrict__ wout,   // [N][3] fp32 slice of w_out, or nullptr
    float* __restrict__ opb,          // partials [4bx][4z][L][3], or nullptr
    int zoff,
    int N, int K, int do_relu,
    int nbx, int nby, int nz) {
  __shared__ __align__(16) ushort S[128 * 64 * 2];   // 32 KB: As | Ws
  __shared__ float woutL[384];
  ushort* As = S;
  ushort* Ws = S + 128 * 64;
  int tid = threadIdx.x;
  int lane = tid & 63, wid = tid >> 6;

  // XCD-aware bijective swizzle (m204)
  int nwg = nbx * nby * nz;
  int gid0 = blockIdx.x;
  int q = nwg >> 3, r = nwg & 7;
  int xcd = gid0 & 7, rank = gid0 >> 3;
  int sid = (xcd < r) ? (xcd * (q + 1) + rank) : (r * (q + 1) + (xcd - r) * q + rank);
  int z = sid / (nbx * nby);
  int rem = sid - z * (nbx * nby);
  int n0 = (rem % nbx) * 128, r0 = (rem / nbx) * 128;

  A += (size_t)z * sA;
  C += (size_t)z * sC;
  const ushort* a2p = add2 ? add2 + (size_t)z * sAdd2 : nullptr;
  int wr = wid >> 1, wc = wid & 1;
  int ksm = K >> 6;

  f32x4 acc[4][4];
#pragma unroll
  for (int i = 0; i < 4; ++i)
#pragma unroll
    for (int j = 0; j < 4; ++j) acc[i][j] = (f32x4)0.0f;

  for (int t = 0; t < ksm; ++t) {
#pragma unroll
    for (int j = 0; j < 4; ++j) {
      int sig = j * 256 + wid * 64 + lane;
      int rr = sig >> 3, ph = sig & 7, sl = ph ^ (rr & 7);
      gld_lds16(&A[(size_t)(r0 + rr) * K + t * 64 + sl * 8], &As[(size_t)(j * 256 + wid * 64) * 8]);
      gld_lds16(&Wt[(size_t)(n0 + rr) * K + t * 64 + sl * 8], &Ws[(size_t)(j * 256 + wid * 64) * 8]);
    }
    __syncthreads();
#pragma unroll
    for (int ks = 0; ks < 2; ++ks) {
      short8 af[4], bg[4];
#pragma unroll
      for (int fm = 0; fm < 4; ++fm) {
        int row = wr * 64 + fm * 16 + (lane & 15);
        af[fm] = *(const short8*)&As[row * 64 + (((ks * 4 + (lane >> 4)) ^ (row & 7)) * 8)];
      }
#pragma unroll
      for (int fn = 0; fn < 4; ++fn) {
        int nl = wc * 64 + fn * 16 + (lane & 15);
        bg[fn] = *(const short8*)&Ws[nl * 64 + (((ks * 4 + (lane >> 4)) ^ (nl & 7)) * 8)];
      }
#pragma unroll
      for (int fm = 0; fm < 4; ++fm)
#pragma unroll
        for (int fn = 0; fn < 4; ++fn)
          acc[fm][fn] = __builtin_amdgcn_mfma_f32_16x16x32_bf16(af[fm], bg[fn], acc[fm][fn], 0, 0, 0);
    }
    __syncthreads();
  }

  // stage w_out slice (128 cols x 3) to LDS
  if (wout && tid < 128) {
    woutL[tid * 3 + 0] = wout[(size_t)(n0 + tid) * 3 + 0];
    woutL[tid * 3 + 1] = wout[(size_t)(n0 + tid) * 3 + 1];
    woutL[tid * 3 + 2] = wout[(size_t)(n0 + tid) * 3 + 2];
  }

  // vectorized epilogue via LDS staging
  float* Ls = (float*)S;   // [32][132] f32
  int row = tid >> 3;
  int c0 = (tid & 7) * 16;
#pragma unroll
  for (int fm = 0; fm < 4; ++fm) {
    if (fm) __syncthreads();
#pragma unroll
    for (int fn = 0; fn < 4; ++fn)
#pragma unroll
      for (int reg = 0; reg < 4; ++reg) {
        int lr = wr * 16 + (lane >> 4) * 4 + reg;
        int lc = wc * 64 + fn * 16 + (lane & 15);
        Ls[lr * 132 + lc] = acc[fm][fn][reg];
      }
    __syncthreads();
    int gr = r0 + (row >> 4) * 64 + fm * 16 + (row & 15);
    float so0 = 0.0f, so1 = 0.0f, so2 = 0.0f;
#pragma unroll
    for (int hh = 0; hh < 2; ++hh) {
      int cc = c0 + hh * 8;
      float v[8];
#pragma unroll
      for (int j = 0; j < 8; ++j) v[j] = Ls[row * 132 + cc + j];
      if (bias) {
#pragma unroll
        for (int j = 0; j < 8; ++j) v[j] += bias[n0 + cc + j];
      }
      if (add1) {
        short8 a1 = *(const short8*)&add1[(size_t)gr * N + n0 + cc];
#pragma unroll
        for (int j = 0; j < 8; ++j) v[j] += bf2f((ushort)a1[j]);
      }
      if (do_relu) {
#pragma unroll
        for (int j = 0; j < 8; ++j) v[j] = fmaxf(v[j], 0.0f);
      }
      if (a2p) {
        short8 a2 = *(const short8*)&a2p[(size_t)gr * N + n0 + cc];
#pragma unroll
        for (int j = 0; j < 8; ++j) v[j] += bf2f((ushort)a2[j]);
      }
      if (wout) {
#pragma unroll
        for (int j = 0; j < 8; ++j) {
          so0 = fmaf(v[j], woutL[(cc + j) * 3 + 0], so0);
          so1 = fmaf(v[j], woutL[(cc + j) * 3 + 1], so1);
          so2 = fmaf(v[j], woutL[(cc + j) * 3 + 2], so2);
        }
      }
      short8 ov;
#pragma unroll
      for (int j = 0; j < 8; ++j) ov[j] = (short)f2bf(v[j]);
      *(short8*)&C[(size_t)gr * N + n0 + cc] = ov;
    }
    if (wout) {
      so0 += __shfl_down(so0, 4); so1 += __shfl_down(so1, 4); so2 += __shfl_down(so2, 4);
      so0 += __shfl_down(so0, 2); so1 += __shfl_down(so1, 2); so2 += __shfl_down(so2, 2);
      so0 += __shfl_down(so0, 1); so1 += __shfl_down(so1, 1); so2 += __shfl_down(so2, 1);
      if ((tid & 7) == 0) {
        int bx = n0 >> 7;
        size_t oi = (((size_t)bx * 4 + (zoff + z)) * L_N + gr) * 3;
        opb[oi + 0] = so0; opb[oi + 1] = so1; opb[oi + 2] = so2;
      }
    }
  }
}

// ---------- reduce out partials: out[z][l] = sum over 3 slots x 4 bx + biases ----------
__global__ __launch_bounds__(256) void k_outred(const float* __restrict__ opb,
                                                const float* __restrict__ b_out,
                                                float* __restrict__ out) {
  int i = blockIdx.x * 256 + threadIdx.x;  // z*L + l
  if (i >= B_N * L_N) return;
  float a0 = b_out[0] + b_out[3] + b_out[6];
  float a1 = b_out[1] + b_out[4] + b_out[7];
  float a2 = b_out[2] + b_out[5] + b_out[8];
  const size_t SS = (size_t)4 * B_N * L_N * 3;  // slot stride
#pragma unroll
  for (int slot = 0; slot < 3; ++slot)
#pragma unroll
    for (int bx = 0; bx < 4; ++bx) {
      const float* p = opb + slot * SS + (((size_t)bx * B_N * L_N) + i) * 3;
      a0 += p[0]; a1 += p[1]; a2 += p[2];
    }
  out[(size_t)i * 3 + 0] = a0;
  out[(size_t)i * 3 + 1] = a1;
  out[(size_t)i * 3 + 2] = a2;
}

// ---------- kv rearrange ----------
__global__ __launch_bounds__(256) void k_rearr(const ushort* __restrict__ kvtmp,
                                               ushort* __restrict__ kbuf,
                                               ushort* __restrict__ vtb) {
  int i = blockIdx.x * 256 + threadIdx.x;
  int col = i & 255, row = i >> 8;
  int b = row >> 8, m = row & 255;
  ushort v = kvtmp[i];
  if (col < 128)
    kbuf[((size_t)b * 256 + m) * 128 + col] = v;
  else
    vtb[(size_t)b * 128 * 256 + (size_t)(col - 128) * 256 + m] = v;
}

// ---------- MFMA attention per (b, head) ----------
__global__ __launch_bounds__(256) void k_attn_m(const ushort* __restrict__ qbuf,
                                                const float* __restrict__ tbuf,
                                                const ushort* __restrict__ kbuf,
                                                const ushort* __restrict__ vtb,
                                                ushort* __restrict__ attn) {
  __shared__ __align__(16) ushort Kt[256 * 64];
  __shared__ __align__(16) ushort Vt[64 * 256];
  __shared__ __align__(16) ushort Qs[64 * 64];
  __shared__ __align__(16) ushort Pw[4][16 * 40];
  __shared__ float ts[64];
  int tid = threadIdx.x;
  int lane = tid & 63, wid = tid >> 6;
  int l0 = blockIdx.x * 64;
  int h = blockIdx.y;
  int z = blockIdx.z;
  const ushort* kbuf_b = kbuf + (size_t)z * M_N * 128;
  const ushort* vtb_b = vtb + (size_t)z * 128 * M_N;
  ushort* attn_b = attn + (size_t)z * L_N * 128;
#pragma unroll
  for (int j = 0; j < 8; ++j) {
    int sig = j * 256 + wid * 64 + lane;
    int m = sig >> 3, ph = sig & 7, sl = ph ^ (m & 7);
    gld_lds16(&kbuf_b[(size_t)m * 128 + h * 64 + sl * 8], &Kt[(size_t)(j * 256 + wid * 64) * 8]);
  }
#pragma unroll
  for (int j = 0; j < 8; ++j) {
    int sig = j * 256 + wid * 64 + lane;
    int d = sig >> 5, ph = sig & 31, sl = ph ^ ((d & 7) << 2);
    gld_lds16(&vtb_b[(size_t)(h * 64 + d) * 256 + sl * 8], &Vt[(size_t)(j * 256 + wid * 64) * 8]);
  }
#pragma unroll
  for (int j = 0; j < 2; ++j) {
    int sig = j * 256 + wid * 64 + lane;
    int q = sig >> 3, ph = sig & 7, sl = ph ^ (q & 7);
    gld_lds16(&qbuf[(size_t)(l0 + q) * 128 + h * 64 + sl * 8], &Qs[(size_t)(j * 256 + wid * 64) * 8]);
  }
  if (tid < 64) ts[tid] = tbuf[l0 + tid];
  __syncthreads();

  f32x4 s_acc[16];
#pragma unroll
  for (int fn = 0; fn < 16; ++fn) s_acc[fn] = (f32x4)0.0f;
#pragma unroll
  for (int ks = 0; ks < 2; ++ks) {
    int qrow = wid * 16 + (lane & 15);
    short8 aq = *(const short8*)&Qs[qrow * 64 + (((ks * 4 + (lane >> 4)) ^ (qrow & 7)) * 8)];
#pragma unroll
    for (int fn = 0; fn < 16; ++fn) {
      int m = fn * 16 + (lane & 15);
      short8 bk = *(const short8*)&Kt[m * 64 + (((ks * 4 + (lane >> 4)) ^ (m & 7)) * 8)];
      s_acc[fn] = __builtin_amdgcn_mfma_f32_16x16x32_bf16(aq, bk, s_acc[fn], 0, 0, 0);
    }
  }
  float mx[4] = {-1e30f, -1e30f, -1e30f, -1e30f};
#pragma unroll
  for (int fn = 0; fn < 16; ++fn) {
#pragma unroll
    for (int reg = 0; reg < 4; ++reg) {
      int ql = wid * 16 + (lane >> 4) * 4 + reg;
      int m = fn * 16 + (lane & 15);
      float mp = ((float)m + 0.5f) * (1.0f / 256.0f);
      float d = ts[ql] - mp;
      float v = s_acc[fn][reg] * 0.125f - 10.0f * d * d;
      s_acc[fn][reg] = v;
      mx[reg] = fmaxf(mx[reg], v);
    }
  }
#pragma unroll
  for (int reg = 0; reg < 4; ++reg) {
    mx[reg] = fmaxf(mx[reg], __shfl_xor(mx[reg], 1));
    mx[reg] = fmaxf(mx[reg], __shfl_xor(mx[reg], 2));
    mx[reg] = fmaxf(mx[reg], __shfl_xor(mx[reg], 4));
    mx[reg] = fmaxf(mx[reg], __shfl_xor(mx[reg], 8));
  }
  float sm[4] = {0.0f, 0.0f, 0.0f, 0.0f};
#pragma unroll
  for (int fn = 0; fn < 16; ++fn) {
#pragma unroll
    for (int reg = 0; reg < 4; ++reg) {
      float e = __expf(s_acc[fn][reg] - mx[reg]);
      s_acc[fn][reg] = e;
      sm[reg] += e;
    }
  }
#pragma unroll
  for (int reg = 0; reg < 4; ++reg) {
    sm[reg] += __shfl_xor(sm[reg], 1);
    sm[reg] += __shfl_xor(sm[reg], 2);
    sm[reg] += __shfl_xor(sm[reg], 4);
    sm[reg] += __shfl_xor(sm[reg], 8);
  }
  float inv[4];
#pragma unroll
  for (int reg = 0; reg < 4; ++reg) inv[reg] = 1.0f / sm[reg];

  f32x4 o_acc[4];
#pragma unroll
  for (int fn = 0; fn < 4; ++fn) o_acc[fn] = (f32x4)0.0f;
  for (int kk = 0; kk < 8; ++kk) {
#pragma unroll
    for (int fp = 0; fp < 2; ++fp) {
      int fn = kk * 2 + fp;
#pragma unroll
      for (int reg = 0; reg < 4; ++reg) {
        int ql16 = (lane >> 4) * 4 + reg;
        int mc = fp * 16 + (lane & 15);
        Pw[wid][ql16 * 40 + mc] = f2bf(s_acc[fn][reg] * inv[reg]);
      }
    }
    asm volatile("s_waitcnt lgkmcnt(0)" ::: "memory");
    __builtin_amdgcn_sched_barrier(0);
    short8 pa = *(const short8*)&Pw[wid][(lane & 15) * 40 + (lane >> 4) * 8];
#pragma unroll
    for (int fn = 0; fn < 4; ++fn) {
      int dr = fn * 16 + (lane & 15);
      short8 vb = *(const short8*)&Vt[dr * 256 + (((kk * 4 + (lane >> 4)) ^ ((dr & 7) << 2)) * 8)];
      o_acc[fn] = __builtin_amdgcn_mfma_f32_16x16x32_bf16(pa, vb, o_acc[fn], 0, 0, 0);
    }
    asm volatile("s_waitcnt lgkmcnt(0)" ::: "memory");
    __builtin_amdgcn_sched_barrier(0);
  }
#pragma unroll
  for (int fn = 0; fn < 4; ++fn)
#pragma unroll
    for (int reg = 0; reg < 4; ++reg) {
      int ql = l0 + wid * 16 + (lane >> 4) * 4 + reg;
      attn_b[(size_t)ql * 128 + h * 64 + fn * 16 + (lane & 15)] = f2bf(o_acc[fn][reg]);
    }
}

extern "C" void kernel_launch(void* const* d_in, const int* in_sizes, int n_in,
                              void* d_out, int out_size, void* d_ws, size_t ws_size,
                              hipStream_t stream) {
  const float* x        = (const float*)d_in[0];
  const float* tokens   = (const float*)d_in[1];
  const float* w_query  = (const float*)d_in[2];
  const float* b_query  = (const float*)d_in[3];
  const float* w_to_q   = (const float*)d_in[4];
  const float* w_to_kv  = (const float*)d_in[5];
  const float* w_to_out = (const float*)d_in[6];
  const float* b_to_out = (const float*)d_in[7];
  const float* w_band   = (const float*)d_in[8];
  const float* b_band   = (const float*)d_in[9];
  const float* w_mod    = (const float*)d_in[10];
  const float* b_mod    = (const float*)d_in[11];
  const float* w_hv     = (const float*)d_in[12];
  const float* b_hv     = (const float*)d_in[13];
  const float* w_out    = (const float*)d_in[14];
  const float* b_out    = (const float*)d_in[15];
  const int* Dd = (const int*)d_in[16];
  const int* Hh = (const int*)d_in[17];
  const int* Ww = (const int*)d_in[18];
  const int* Tt = (const int*)d_in[19];
  float* out = (float*)d_out;

  ushort* W = (ushort*)d_ws;
  size_t o = 0;
  auto alloc = [&](size_t n) { ushort* p = W + o; o += n; return p; };
  const size_t big = (size_t)L_N * HID_N;   // 8388608
  const size_t LQ = (size_t)L_N * 128;      // 2097152
  const size_t OPB_U = (size_t)3 * 4 * B_N * L_N * 3 * 2;  // 3 slots x 4 bx x 4z x L x 3 f32, in ushorts

  ushort* gamma  = alloc(4 * LQ);
  ushort* qb     = alloc(LQ);
  ushort* attnout= alloc(4 * LQ);
  ushort* tokb   = alloc((size_t)B_N * M_N * HID_N);
  ushort* kbuf   = alloc((size_t)B_N * M_N * 128);
  ushort* vtb    = alloc((size_t)B_N * 128 * M_N);
  ushort* wq_t   = alloc(512 * 128);
  ushort* wtq_t  = alloc(128 * 512);
  ushort* wkv_t  = alloc(256 * 512);
  ushort* wto_t  = alloc(512 * 128);
  ushort* wb_t   = alloc(3 * 512 * 128);
  ushort* wm_t   = alloc(3 * 512 * 512);
  ushort* whv_t  = alloc(2 * 512 * 512);
  float* tbuf    = (float*)alloc(L_N * 2);
  size_t base_u = o;

  // batched: single hband buffer (recomputed per kk) + opb aliased over attnout
  size_t need_batched = (base_u + big + 3 * 4 * big) * sizeof(ushort);
  bool batched = ws_size >= need_batched;

  ushort* hband; float* opb; ushort *modv, *hv, *tmp;
  if (batched) {
    hband = alloc(big);
    modv = alloc(4 * big); hv = alloc(4 * big); tmp = alloc(4 * big);
    opb = (float*)attnout;                    // attnout dead after modv-GEMM
  } else {
    hband = alloc(3 * big);
    opb = (float*)alloc(OPB_U);
    modv = alloc(big); hv = alloc(big); tmp = alloc(big);
  }
  ushort* xq = modv;        // alias: xq dead before modv written
  ushort* kvtmp = attnout;  // alias: consumed before attnout written

  const long long SL = (long long)big;
  const long long SQ = (long long)LQ;
  const size_t SLOT = (size_t)4 * B_N * L_N * 3;  // opb slot stride (floats)

  // ---- prep ----
  k_wt_all<<<dim3(1792), 256, 0, stream>>>(w_query, w_to_q, w_to_kv, w_to_out, w_band, w_mod, w_hv,
                                           wq_t, wtq_t, wkv_t, wto_t, wb_t, wm_t, whv_t);
  k_cvt<<<dim3(512), 256, 0, stream>>>(tokens, tokb, B_N * M_N * HID_N / 4);
  k_gamma<<<dim3(L_N / 16, 4), 256, 0, stream>>>(x, gamma);
  k_tpos<<<dim3(L_N / 256), 256, 0, stream>>>(x, Dd, Hh, Ww, Tt, tbuf);

  // ---- pre-pass ----
  k_gemm2<<<dim3(4 * 128), 256, 0, stream>>>(gamma, 0, wq_t, b_query, nullptr, nullptr, 0,
                                             xq, 0, nullptr, nullptr, 0, 512, 128, 1, 4, 128, 1);
  k_gemm2<<<dim3(1 * 128), 256, 0, stream>>>(xq, 0, wtq_t, nullptr, nullptr, nullptr, 0,
                                             qb, 0, nullptr, nullptr, 0, 128, 512, 0, 1, 128, 1);
  k_gemm2<<<dim3(2 * 8), 256, 0, stream>>>(tokb, 0, wkv_t, nullptr, nullptr, nullptr, 0,
                                           kvtmp, 0, nullptr, nullptr, 0, 256, 512, 0, 2, 8, 1);
  k_rearr<<<dim3(1024), 256, 0, stream>>>(kvtmp, kbuf, vtb);
  k_attn_m<<<dim3(L_N / 64, 2, 4), 256, 0, stream>>>(qb, tbuf, kbuf, vtb, attnout);

  if (batched) {
    k_gemm2<<<dim3(4 * 128 * 4), 256, 0, stream>>>(attnout, SQ, wto_t, b_to_out, nullptr, nullptr, 0,
                                                   modv, SL, nullptr, nullptr, 0, 512, 128, 0, 4, 128, 4);
    for (int kk = 0; kk < 3; ++kk) {
      k_gemm2<<<dim3(4 * 128), 256, 0, stream>>>(gamma + (size_t)(1 + kk) * LQ, 0,
                                                 wb_t + (size_t)kk * 65536, b_band + kk * 512,
                                                 nullptr, nullptr, 0, hband, 0,
                                                 nullptr, nullptr, 0, 512, 128, 1, 4, 128, 1);
      if (kk == 0) {
        k_gemm2<<<dim3(4 * 128 * 4), 256, 0, stream>>>(modv, SL, wm_t, b_mod, hband, nullptr, 0,
                                                       hv, SL, w_out, opb, 0, 512, 512, 1, 4, 128, 4);
      } else {
        k_gemm2<<<dim3(4 * 128 * 4), 256, 0, stream>>>(modv, SL, wm_t + (size_t)kk * 262144,
                                                       b_mod + kk * 512, hband, hv, SL,
                                                       tmp, SL, nullptr, nullptr, 0, 512, 512, 1, 4, 128, 4);
        k_gemm2<<<dim3(4 * 128 * 4), 256, 0, stream>>>(tmp, SL, whv_t + (size_t)(kk - 1) * 262144,
                                                       b_hv + (kk - 1) * 512, nullptr, nullptr, 0,
                                                       hv, SL, w_out + (size_t)kk * 1536,
                                                       opb + (size_t)kk * SLOT, 0, 512, 512, 1, 4, 128, 4);
      }
    }
  } else {
    for (int kk = 0; kk < 3; ++kk)
      k_gemm2<<<dim3(4 * 128), 256, 0, stream>>>(gamma + (size_t)(1 + kk) * LQ, 0,
                                                 wb_t + (size_t)kk * 65536, b_band + kk * 512,
                                                 nullptr, nullptr, 0, hband + (size_t)kk * big, 0,
                                                 nullptr, nullptr, 0, 512, 128, 1, 4, 128, 1);
    for (int z = 0; z < B_N; ++z) {
      k_gemm2<<<dim3(4 * 128), 256, 0, stream>>>(attnout + (size_t)z * LQ, 0, wto_t, b_to_out,
                                                 nullptr, nullptr, 0, modv, 0,
                                                 nullptr, nullptr, 0, 512, 128, 0, 4, 128, 1);
      k_gemm2<<<dim3(4 * 128), 256, 0, stream>>>(modv, 0, wm_t, b_mod, hband, nullptr, 0,
                                                 hv, 0, w_out, opb, z, 512, 512, 1, 4, 128, 1);
      for (int kk = 1; kk < 3; ++kk) {
        k_gemm2<<<dim3(4 * 128), 256, 0, stream>>>(modv, 0, wm_t + (size_t)kk * 262144,
                                                   b_mod + kk * 512, hband + (size_t)kk * big, hv, 0,
                                                   tmp, 0, nullptr, nullptr, 0, 512, 512, 1, 4, 128, 1);
        k_gemm2<<<dim3(4 * 128), 256, 0, stream>>>(tmp, 0, whv_t + (size_t)(kk - 1) * 262144,
                                                   b_hv + (kk - 1) * 512, nullptr, nullptr, 0,
                                                   hv, 0, w_out + (size_t)kk * 1536,
                                                   opb + (size_t)kk * SLOT, z, 512, 512, 1, 4, 128, 1);
      }
    }
  }
  k_outred<<<dim3((B_N * L_N + 255) / 256), 256, 0, stream>>>(opb, b_out, out);
}